// Round 4
// baseline (3887.918 us; speedup 1.0000x reference)
//
#include <hip/hip_runtime.h>
#include <hip/hip_bf16.h>

// ============================================================================
// Bidirectional 2-layer GRU encoder (Keras reset_after=True), MI355X/gfx950.
// Numerics: split-bf16 (hi+lo, 3-product MFMA) EVERYWHERE a matmul operand
// appears (embedding/x0, Wx0, out0, Wx1, h, Wh). Residual error ~1e-4.
// Structure:
//   1. transpose+bf16-split weights
//   2. embed: x0 hi/lo [t*32+b][512] = split(E[x[b][t]])
//   3. gemm_bias: xg = x0 @ Wx + b[0]  (f32 out, [T*B][1536], row = t*32+b)
//   4. gru_scan (persistent, 32 blocks = 2 dirs x 16 WGs, flag barrier/step)
//      h state: f32 in owner registers; hi+lo bf16 broadcast buffers (global)
//      Wh slice resident in registers (hi+lo, 32 B-frags = 128 VGPR)
//   5. repeat 3,4 for layer 1
// Cross-WG sync: plain data stores + release/acquire flags (agent scope).
// ============================================================================

typedef __attribute__((ext_vector_type(8))) short short8;
typedef __attribute__((ext_vector_type(8))) __bf16 bf16x8;
typedef __attribute__((ext_vector_type(4))) float f32x4;
typedef __attribute__((ext_vector_type(4))) int i32x4;
typedef __attribute__((ext_vector_type(2))) float f32x2;

#define DEVINLINE __device__ __forceinline__

static constexpr int B = 32, T = 256, U = 512, NG = 1536;
static constexpr int BU = B * U;             // 16384
static constexpr long OUT_ELEMS = 8388608;   // 32*256*1024
static constexpr float SCALE_BN = 0.9995003746879552f;  // 1/sqrt(1+1e-3)

DEVINLINE unsigned bfbits(float f) {
  unsigned u = __float_as_uint(f);
  return (u + 0x7fffu + ((u >> 16) & 1u)) >> 16;
}
DEVINLINE float bf2f(unsigned bits) { return __uint_as_float(bits << 16); }
// split v into hi (bf16 bits) and lo (bf16 bits of residual)
DEVINLINE void split2(float v, unsigned& hi, unsigned& lo) {
  hi = bfbits(v);
  lo = bfbits(v - bf2f(hi));
}
DEVINLINE float sigmoidf_(float x) { return 1.f / (1.f + __expf(-x)); }
DEVINLINE float tanhf_(float x) {
  x = fminf(15.f, fmaxf(-15.f, x));
  float e = __expf(2.f * x);
  return (e - 1.f) / (e + 1.f);
}
DEVINLINE f32x4 mfma16(short8 a, short8 b, f32x4 c) {
  return __builtin_amdgcn_mfma_f32_16x16x32_bf16(
      __builtin_bit_cast(bf16x8, a), __builtin_bit_cast(bf16x8, b), c, 0, 0, 0);
}

// ---------------------------------------------------------------------------
// Weight transpose + f32->bf16 hi/lo:  in [K][N] f32 -> oh/ol [N][K] bf16
// ---------------------------------------------------------------------------
__global__ __launch_bounds__(256)
void transpose_w(const float* __restrict__ in, unsigned short* __restrict__ oh,
                 unsigned short* __restrict__ ol, int K, int N) {
  __shared__ float tile[32][33];
  const int n0 = blockIdx.x * 32, k0 = blockIdx.y * 32;
  const int tx = threadIdx.x & 31, ty = threadIdx.x >> 5;  // 32 x 8
  for (int i = ty; i < 32; i += 8)
    tile[i][tx] = in[(long)(k0 + i) * N + n0 + tx];
  __syncthreads();
  for (int i = ty; i < 32; i += 8) {
    const float v = tile[tx][i];
    unsigned hi, lo;
    split2(v, hi, lo);
    oh[(long)(n0 + i) * K + k0 + tx] = (unsigned short)hi;
    ol[(long)(n0 + i) * K + k0 + tx] = (unsigned short)lo;
  }
}

// ---------------------------------------------------------------------------
// Embedding: x0{h,l}[r=t*32+b][0..511] = split(E[x[b][t]][:])
// ---------------------------------------------------------------------------
__global__ __launch_bounds__(256)
void embed_kernel(const int* __restrict__ x, const float* __restrict__ E,
                  unsigned short* __restrict__ xh, unsigned short* __restrict__ xl) {
  const int r = blockIdx.x;            // 0..8191
  const int t = r >> 5, b = r & 31;
  const int id = x[b * T + t];
  const float* src = E + (long)id * 512;
  f32x2 v = *reinterpret_cast<const f32x2*>(src + threadIdx.x * 2);
  unsigned h0, l0, h1, l1;
  split2(v.x, h0, l0);
  split2(v.y, h1, l1);
  ((unsigned*)xh)[(long)r * 256 + threadIdx.x] = h0 | (h1 << 16);
  ((unsigned*)xl)[(long)r * 256 + threadIdx.x] = l0 | (l1 << 16);
}

// ---------------------------------------------------------------------------
// GEMM: C[M=8192][1536] f32 = A[M][K] @ Bt[1536][K]^T + bias
// 128x128 tile, BK=32, 4 waves (2x2), 4x4 16x16x32 MFMA frags per wave.
// A,B given as hi+lo planes; C ~= Ah Bh + Ah Bl + Al Bh.
// ---------------------------------------------------------------------------
template <int K>
__global__ __launch_bounds__(256)
void gemm_bias(const unsigned short* __restrict__ Ah,
               const unsigned short* __restrict__ Al,
               const unsigned short* __restrict__ Bh,
               const unsigned short* __restrict__ Bl,
               const float* __restrict__ bias, float* __restrict__ C) {
  __shared__ __align__(16) unsigned short AsH[128 * 32];
  __shared__ __align__(16) unsigned short BsH[128 * 32];
  __shared__ __align__(16) unsigned short AsL[128 * 32];
  __shared__ __align__(16) unsigned short BsL[128 * 32];
  const int m0 = blockIdx.x * 128, n0 = blockIdx.y * 128;
  const int tid = threadIdx.x, lane = tid & 63, wave = tid >> 6;
  const int wr = wave >> 1, wc = wave & 1, lr = lane & 15, kq = lane >> 4;
  f32x4 acc[4][4] = {};
  for (int kt = 0; kt < K / 32; ++kt) {
    const int k0 = kt * 32;
    i32x4 vah[2], vbh[2], val[2], vbl[2];
#pragma unroll
    for (int u = 0; u < 2; ++u) {
      const int idx = tid + u * 256, row = idx >> 2, sub = idx & 3;
      vah[u] = *reinterpret_cast<const i32x4*>(Ah + (long)(m0 + row) * K + k0 + sub * 8);
      vbh[u] = *reinterpret_cast<const i32x4*>(Bh + (long)(n0 + row) * K + k0 + sub * 8);
      val[u] = *reinterpret_cast<const i32x4*>(Al + (long)(m0 + row) * K + k0 + sub * 8);
      vbl[u] = *reinterpret_cast<const i32x4*>(Bl + (long)(n0 + row) * K + k0 + sub * 8);
    }
    __syncthreads();
#pragma unroll
    for (int u = 0; u < 2; ++u) {
      const int idx = tid + u * 256;
      *reinterpret_cast<i32x4*>(AsH + idx * 8) = vah[u];
      *reinterpret_cast<i32x4*>(BsH + idx * 8) = vbh[u];
      *reinterpret_cast<i32x4*>(AsL + idx * 8) = val[u];
      *reinterpret_cast<i32x4*>(BsL + idx * 8) = vbl[u];
    }
    __syncthreads();
    short8 afh[4], bfh[4], afl[4], bfl[4];
#pragma unroll
    for (int i = 0; i < 4; ++i) {
      afh[i] = *reinterpret_cast<const short8*>(AsH + (wr * 64 + i * 16 + lr) * 32 + kq * 8);
      bfh[i] = *reinterpret_cast<const short8*>(BsH + (wc * 64 + i * 16 + lr) * 32 + kq * 8);
      afl[i] = *reinterpret_cast<const short8*>(AsL + (wr * 64 + i * 16 + lr) * 32 + kq * 8);
      bfl[i] = *reinterpret_cast<const short8*>(BsL + (wc * 64 + i * 16 + lr) * 32 + kq * 8);
    }
#pragma unroll
    for (int i = 0; i < 4; ++i)
#pragma unroll
      for (int j = 0; j < 4; ++j) {
        acc[i][j] = mfma16(afh[i], bfh[j], acc[i][j]);
        acc[i][j] = mfma16(afh[i], bfl[j], acc[i][j]);
        acc[i][j] = mfma16(afl[i], bfh[j], acc[i][j]);
      }
  }
#pragma unroll
  for (int j = 0; j < 4; ++j) {
    const int col = n0 + wc * 64 + j * 16 + lr;
    const float bv = bias[col];
#pragma unroll
    for (int i = 0; i < 4; ++i) {
      const int row0 = m0 + wr * 64 + i * 16 + kq * 4;
#pragma unroll
      for (int r = 0; r < 4; ++r)
        C[(long)(row0 + r) * NG + col] = acc[i][j][r] + bv;
    }
  }
}

// ---------------------------------------------------------------------------
// Persistent GRU scan, one layer, both directions.
// Grid = 32 blocks: dir = bid>>4, wg = bid&15 owns hidden units [wg*32, +32).
// 384 threads = 6 waves; wave (g = w>>1, half = w&1) owns Wh cols
// g*512 + j0 + half*16 .. +16, hi+lo weights resident (32 B-frags, 128 VGPR).
// Per step:
//   1. prefetch xg slice into regs      2. stage bcast h (hi+lo bf16) -> LDS
//   3. MFMA rg = h @ Wh + b[1] (3-prod) 4. gates in f32 (state in f32 regs)
//   5. write own hi+lo h-slice + outputs; release flag; acquire 16 flags.
// ---------------------------------------------------------------------------
__global__ __launch_bounds__(384, 1)
void gru_scan(const float* __restrict__ xgf, const float* __restrict__ xgb,
              const unsigned short* __restrict__ whtfh,
              const unsigned short* __restrict__ whtfl,
              const unsigned short* __restrict__ whtbh,
              const unsigned short* __restrict__ whtbl,
              const float* __restrict__ rbf, const float* __restrict__ rbb,
              const float* __restrict__ h0L,    // [2][B][U] this layer, f32
              unsigned short* __restrict__ hbh, // [2 dir][2 par][BU] bf16 hi
              unsigned short* __restrict__ hbl, // [2 dir][2 par][BU] bf16 lo
              int* __restrict__ flags,          // [2 dirs][16]
              unsigned short* __restrict__ out0h, // layer0: bf16 hi [T*B][1024]
              unsigned short* __restrict__ out0l, // layer0: bf16 lo
              float* __restrict__ outF,           // layer1: f32 d_out
              float* __restrict__ hT,             // d_out tail for this layer
              const int layer) {
  const int dir = blockIdx.x >> 4, wg = blockIdx.x & 15;
  const int j0 = wg * 32;
  const int tid = threadIdx.x, wave = tid >> 6, lane = tid & 63;
  const int lr = lane & 15, kq = lane >> 4;
  const float* xg = dir ? xgb : xgf;
  const unsigned short* wth = dir ? whtbh : whtfh;
  const unsigned short* wtl = dir ? whtbl : whtfl;
  const float* rb = dir ? rbb : rbf;
  const float* h0d = h0L + dir * BU;
  unsigned short* hbhd = hbh + dir * 2 * BU;
  unsigned short* hbld = hbl + dir * 2 * BU;
  int* flg = flags + dir * 16;

  __shared__ __align__(16) unsigned short h_hi[32][520];
  __shared__ __align__(16) unsigned short h_lo[32][520];
  __shared__ float rg_lds[32][97];

  // Preload this wave's Wh slice (hi+lo) as MFMA B-fragments.
  const int g = wave >> 1, half = wave & 1;
  const int c0 = g * 512 + j0 + half * 16;   // global Wh column base
  short8 wfh[16], wfl[16];
#pragma unroll
  for (int kk = 0; kk < 16; ++kk) {
    wfh[kk] = *reinterpret_cast<const short8*>(wth + (long)(c0 + lr) * 512 + kk * 32 + kq * 8);
    wfl[kk] = *reinterpret_cast<const short8*>(wtl + (long)(c0 + lr) * 512 + kk * 32 + kq * 8);
  }
  const float bv = rb[c0 + lr];

  // Register-carried f32 state for own tasks (task p = b*16 + jpair).
  float hpr[2][2];
#pragma unroll
  for (int q = 0; q < 2; ++q) {
    const int p = tid + q * 384;
    if (p < 512) {
      const int b = p >> 4, jr = (p & 15) * 2;
      hpr[q][0] = h0d[b * U + j0 + jr];
      hpr[q][1] = h0d[b * U + j0 + jr + 1];
    }
  }

  for (int s = 0; s < T; ++s) {
    const int t_in = dir ? (T - 1 - s) : s;
    const int par = s & 1;

    // ---- 1. prefetch this thread's xg gate inputs into registers ----
    f32x2 xv[2][3];
    {
      const long xbase = (long)t_in * 32 * NG;
#pragma unroll
      for (int q = 0; q < 2; ++q) {
        const int p = tid + q * 384;
        if (p < 512) {
          const int b = p >> 4, jr = (p & 15) * 2;
#pragma unroll
          for (int gg = 0; gg < 3; ++gg)
            xv[q][gg] = *reinterpret_cast<const f32x2*>(
                xg + xbase + (long)b * NG + gg * 512 + j0 + jr);
        }
      }
    }

    // ---- 2. stage broadcast h (hi+lo) -> LDS ----
    if (s == 0) {
      for (int p = tid; p < BU / 4; p += 384) {
        const int b = p >> 7, u = (p & 127) * 4;
        f32x4 v = *reinterpret_cast<const f32x4*>(h0d + b * U + u);
        unsigned hi0, lo0, hi1, lo1, hi2, lo2, hi3, lo3;
        split2(v.x, hi0, lo0); split2(v.y, hi1, lo1);
        split2(v.z, hi2, lo2); split2(v.w, hi3, lo3);
        unsigned* dh = reinterpret_cast<unsigned*>(&h_hi[b][u]);
        unsigned* dl = reinterpret_cast<unsigned*>(&h_lo[b][u]);
        dh[0] = hi0 | (hi1 << 16); dh[1] = hi2 | (hi3 << 16);
        dl[0] = lo0 | (lo1 << 16); dl[1] = lo2 | (lo3 << 16);
      }
    } else {
      const unsigned short* hsh = hbhd + par * BU;
      const unsigned short* hsl = hbld + par * BU;
      for (int p = tid; p < BU / 8; p += 384) {
        const int b = p >> 6, u = (p & 63) * 8;
        *reinterpret_cast<i32x4*>(&h_hi[b][u]) =
            *reinterpret_cast<const i32x4*>(hsh + b * U + u);
        *reinterpret_cast<i32x4*>(&h_lo[b][u]) =
            *reinterpret_cast<const i32x4*>(hsl + b * U + u);
      }
    }
    __syncthreads();

    // ---- 3. rg = h @ Wh_slice (+ b[1]), 3-product split-bf16 ----
    f32x4 aHH0 = {}, aHL0 = {}, aLH0 = {}, aHH1 = {}, aHL1 = {}, aLH1 = {};
#pragma unroll
    for (int kk = 0; kk < 16; ++kk) {
      const short8 a0h = *reinterpret_cast<const short8*>(&h_hi[lr][kk * 32 + kq * 8]);
      const short8 a0l = *reinterpret_cast<const short8*>(&h_lo[lr][kk * 32 + kq * 8]);
      const short8 a1h = *reinterpret_cast<const short8*>(&h_hi[16 + lr][kk * 32 + kq * 8]);
      const short8 a1l = *reinterpret_cast<const short8*>(&h_lo[16 + lr][kk * 32 + kq * 8]);
      aHH0 = mfma16(a0h, wfh[kk], aHH0);
      aHL0 = mfma16(a0h, wfl[kk], aHL0);
      aLH0 = mfma16(a0l, wfh[kk], aLH0);
      aHH1 = mfma16(a1h, wfh[kk], aHH1);
      aHL1 = mfma16(a1h, wfl[kk], aHL1);
      aLH1 = mfma16(a1l, wfh[kk], aLH1);
    }
#pragma unroll
    for (int r = 0; r < 4; ++r) {
      rg_lds[kq * 4 + r][wave * 16 + lr] = aHH0[r] + aHL0[r] + aLH0[r] + bv;
      rg_lds[16 + kq * 4 + r][wave * 16 + lr] = aHH1[r] + aHL1[r] + aLH1[r] + bv;
    }
    __syncthreads();

    // ---- 4/5. gates + state update (f32 state in registers) ----
    unsigned short* hdh = hbhd + (1 - par) * BU;
    unsigned short* hdl = hbld + (1 - par) * BU;
#pragma unroll
    for (int q = 0; q < 2; ++q) {
      const int p = tid + q * 384;
      if (p >= 512) break;
      const int b = p >> 4, jr = (p & 15) * 2;
      float hn[2];
#pragma unroll
      for (int e = 0; e < 2; ++e) {
        const int j = jr + e;
        const float xz = xv[q][0][e], xr = xv[q][1][e], xh = xv[q][2][e];
        const float rz = rg_lds[b][j], rr = rg_lds[b][32 + j], rh = rg_lds[b][64 + j];
        const float z = sigmoidf_(xz + rz);
        const float r = sigmoidf_(xr + rr);
        const float hh = tanhf_(xh + r * rh);
        hn[e] = z * hpr[q][e] + (1.f - z) * hh;
      }
      hpr[q][0] = hn[0];
      hpr[q][1] = hn[1];
      unsigned hi0, lo0, hi1, lo1;
      split2(hn[0], hi0, lo0); split2(hn[1], hi1, lo1);
      *reinterpret_cast<unsigned*>(hdh + b * U + j0 + jr) = hi0 | (hi1 << 16);
      *reinterpret_cast<unsigned*>(hdl + b * U + j0 + jr) = lo0 | (lo1 << 16);
      if (layer == 0) {
        const float o0 = hn[0] * SCALE_BN, o1 = hn[1] * SCALE_BN;
        unsigned oh0, ol0, oh1, ol1;
        split2(o0, oh0, ol0); split2(o1, oh1, ol1);
        const long oidx = (((long)s * 32 + b) * 1024 + dir * 512 + j0 + jr) >> 1;
        ((unsigned*)out0h)[oidx] = oh0 | (oh1 << 16);
        ((unsigned*)out0l)[oidx] = ol0 | (ol1 << 16);
      } else {
        float* o = outF + ((long)b * T + s) * 1024 + dir * 512 + j0 + jr;
        o[0] = hn[0] * SCALE_BN;
        o[1] = hn[1] * SCALE_BN;
      }
      if (s == T - 1) {
        float* o = hT + dir * BU + b * U + j0 + jr;
        o[0] = hn[0] * SCALE_BN;
        o[1] = hn[1] * SCALE_BN;
      }
    }
    __syncthreads();
    if (tid == 0)
      __hip_atomic_store(flg + wg, s + 1, __ATOMIC_RELEASE, __HIP_MEMORY_SCOPE_AGENT);
    if (s < T - 1) {
      if (tid < 16) {
        while (__hip_atomic_load(flg + tid, __ATOMIC_ACQUIRE, __HIP_MEMORY_SCOPE_AGENT) < s + 1)
          __builtin_amdgcn_s_sleep(2);
      }
      __syncthreads();
    }
  }
}

extern "C" void kernel_launch(void* const* d_in, const int* in_sizes, int n_in,
                              void* d_out, int out_size, void* d_ws, size_t ws_size,
                              hipStream_t stream) {
  (void)in_sizes; (void)n_in; (void)out_size; (void)ws_size;
  const int*   x    = (const int*)d_in[0];
  const float* h0   = (const float*)d_in[1];
  const float* E    = (const float*)d_in[2];
  const float* Wx0f = (const float*)d_in[3];
  const float* Wh0f = (const float*)d_in[4];
  const float* b0f  = (const float*)d_in[5];
  const float* Wx0b = (const float*)d_in[6];
  const float* Wh0b = (const float*)d_in[7];
  const float* b0b  = (const float*)d_in[8];
  const float* Wx1f = (const float*)d_in[9];
  const float* Wh1f = (const float*)d_in[10];
  const float* b1f  = (const float*)d_in[11];
  const float* Wx1b = (const float*)d_in[12];
  const float* Wh1b = (const float*)d_in[13];
  const float* b1b  = (const float*)d_in[14];
  float* dout = (float*)d_out;

  // ---- workspace carve-up (sequential, ~166 MB total) ----
  char* p = (char*)d_ws;
  auto alloc = [&p](long bytes) { char* r = p; p += (bytes + 255) & ~255L; return r; };
  float* XGF = (float*)alloc(50331648);            // [8192][1536] f32
  float* XGB = (float*)alloc(50331648);
  unsigned short* OUT0H = (unsigned short*)alloc(16777216);  // [8192][1024] bf16
  unsigned short* OUT0L = (unsigned short*)alloc(16777216);
  unsigned short* X0H = OUT0H;  // alias: X0 dead before OUT0 written
  unsigned short* X0L = OUT0L;
  unsigned short* WHT0FH = (unsigned short*)alloc(1572864);  // [1536][512] bf16
  unsigned short* WHT0FL = (unsigned short*)alloc(1572864);
  unsigned short* WHT0BH = (unsigned short*)alloc(1572864);
  unsigned short* WHT0BL = (unsigned short*)alloc(1572864);
  unsigned short* WHT1FH = (unsigned short*)alloc(1572864);
  unsigned short* WHT1FL = (unsigned short*)alloc(1572864);
  unsigned short* WHT1BH = (unsigned short*)alloc(1572864);
  unsigned short* WHT1BL = (unsigned short*)alloc(1572864);
  unsigned short* WXT0FH = (unsigned short*)alloc(1572864);
  unsigned short* WXT0FL = (unsigned short*)alloc(1572864);
  unsigned short* WXT0BH = (unsigned short*)alloc(1572864);
  unsigned short* WXT0BL = (unsigned short*)alloc(1572864);
  unsigned short* WXT1FH = (unsigned short*)alloc(3145728);  // [1536][1024]
  unsigned short* WXT1FL = (unsigned short*)alloc(3145728);
  unsigned short* WXT1BH = (unsigned short*)alloc(3145728);
  unsigned short* WXT1BL = (unsigned short*)alloc(3145728);
  unsigned short* HBH = (unsigned short*)alloc(131072);  // [2][2][BU] bf16
  unsigned short* HBL = (unsigned short*)alloc(131072);
  int* FLAGS = (int*)alloc(256);

  hipMemsetAsync(FLAGS, 0, 256, stream);

  dim3 blk(256);
  transpose_w<<<dim3(48, 16), blk, 0, stream>>>(Wh0f, WHT0FH, WHT0FL, 512, NG);
  transpose_w<<<dim3(48, 16), blk, 0, stream>>>(Wh0b, WHT0BH, WHT0BL, 512, NG);
  transpose_w<<<dim3(48, 16), blk, 0, stream>>>(Wh1f, WHT1FH, WHT1FL, 512, NG);
  transpose_w<<<dim3(48, 16), blk, 0, stream>>>(Wh1b, WHT1BH, WHT1BL, 512, NG);
  transpose_w<<<dim3(48, 16), blk, 0, stream>>>(Wx0f, WXT0FH, WXT0FL, 512, NG);
  transpose_w<<<dim3(48, 16), blk, 0, stream>>>(Wx0b, WXT0BH, WXT0BL, 512, NG);
  transpose_w<<<dim3(48, 32), blk, 0, stream>>>(Wx1f, WXT1FH, WXT1FL, 1024, NG);
  transpose_w<<<dim3(48, 32), blk, 0, stream>>>(Wx1b, WXT1BH, WXT1BL, 1024, NG);

  embed_kernel<<<dim3(8192), blk, 0, stream>>>(x, E, X0H, X0L);

  // layer 0
  gemm_bias<512><<<dim3(64, 12), blk, 0, stream>>>(
      X0H, X0L, WXT0FH, WXT0FL, b0f, XGF);
  gemm_bias<512><<<dim3(64, 12), blk, 0, stream>>>(
      X0H, X0L, WXT0BH, WXT0BL, b0b, XGB);
  gru_scan<<<dim3(32), dim3(384), 0, stream>>>(
      XGF, XGB, WHT0FH, WHT0FL, WHT0BH, WHT0BL, b0f + NG, b0b + NG, h0,
      HBH, HBL, FLAGS, OUT0H, OUT0L, nullptr, dout + OUT_ELEMS, 0);

  // layer 1
  gemm_bias<1024><<<dim3(64, 12), blk, 0, stream>>>(
      OUT0H, OUT0L, WXT1FH, WXT1FL, b1f, XGF);
  gemm_bias<1024><<<dim3(64, 12), blk, 0, stream>>>(
      OUT0H, OUT0L, WXT1BH, WXT1BL, b1b, XGB);
  gru_scan<<<dim3(32), dim3(384), 0, stream>>>(
      XGF, XGB, WHT1FH, WHT1FL, WHT1BH, WHT1BL, b1f + NG, b1b + NG, h0 + 2 * BU,
      HBH, HBL, FLAGS + 32, nullptr, nullptr, dout, dout + OUT_ELEMS + 2 * BU, 1);
}